// Round 10
// baseline (340.372 us; speedup 1.0000x reference)
//
#include <hip/hip_runtime.h>
#include <stdint.h>

#define GRID_Z 10
#define GRID_Y 400
#define GRID_X 352
#define NGRID (GRID_Z * GRID_Y * GRID_X)   // 1,408,000
#define NVOX 200000
#define CCH 128
#define MROI 64
#define GXD 64
#define GYD 32
#define GZD 4
#define GCELLS 8192                         // GXD*GYD*GZD
#define NTAPS 147                           // 7*7*3
#define FPAD 132                            // feat LDS row pitch (128+4)
#define TROWS 32                            // voxel rows per tile

// Recompute a grid cell's world xyz exactly like the reference (fp32, no fma
// contraction so floor() boundaries match XLA's mul+add evaluation).
__device__ __forceinline__ void cell_xyz(const float* __restrict__ roi, int g,
                                         float& X, float& Y, float& Z) {
#pragma clang fp contract(off)
    int iz = g & 3;
    int iy = (g >> 2) & 31;
    int ix = g >> 7;
    float bx = roi[3] * 2.0f;   // EXTEND on x,y dims
    float by = roi[4] * 2.0f;
    float bz = roi[5];
    float lx = (ix + 0.5f) / 64.0f * bx - bx / 2.0f;
    float ly = (iy + 0.5f) / 32.0f * by - by / 2.0f;
    float lz = (iz + 0.5f) / 4.0f  * bz - bz / 2.0f;
    float c = cosf(roi[6]);
    float s = sinf(roi[6]);
    X = lx * c + ly * (-s) + roi[0];
    Y = lx * s + ly * c    + roi[1];
    Z = lz + roi[2];
}

// Same math with the block-uniform ROI terms hoisted (values identical).
__device__ __forceinline__ int cell_probe(float bx, float by, float bz,
                                          float cs, float sn,
                                          float ox, float oy, float oz,
                                          int g, const int* __restrict__ v2p) {
#pragma clang fp contract(off)
    int iz = g & 3;
    int iy = (g >> 2) & 31;
    int ix = g >> 7;
    float lx = (ix + 0.5f) / 64.0f * bx - bx / 2.0f;
    float ly = (iy + 0.5f) / 32.0f * by - by / 2.0f;
    float lz = (iz + 0.5f) / 4.0f  * bz - bz / 2.0f;
    float X = lx * cs + ly * (-sn) + ox;
    float Y = lx * sn + ly * cs    + oy;
    float Z = lz + oz;
    float fx = floorf((X - 0.0f)     / 0.05f);
    float fy = floorf((Y - (-40.0f)) / 0.05f);
    float fz = floorf((Z - (-3.0f))  / 0.1f);
    int cx = (int)floorf(fx / 4.0f);
    int cy = (int)floorf(fy / 4.0f);
    int cz = (int)floorf(fz / 4.0f);
    int p = -1;
    if (cz >= 0 && cz < GRID_Z && cy >= 0 && cy < GRID_Y && cx >= 0 && cx < GRID_X)
        p = v2p[(cz * GRID_Y + cy) * GRID_X + cx];
    return p;
}

__global__ void k_scatter(const int* __restrict__ vcoords, int* __restrict__ v2p,
                          int* __restrict__ done) {
    int i = blockIdx.x * 256 + threadIdx.x;
    if (blockIdx.x == 0 && threadIdx.x < MROI) done[threadIdx.x] = 0;  // fold memset
    if (i >= NVOX) return;
    int z = vcoords[i * 4 + 1];
    int y = vcoords[i * 4 + 2];
    int x = vcoords[i * 4 + 3];
    // Duplicate coords: XLA scatter applies updates in order -> last (max idx) wins.
    atomicMax(&v2p[(z * GRID_Y + y) * GRID_X + x], i);
}

// Fused build + dots + last-block merge. Grid = NS*MROI blocks; block (s,m):
//   A) builds its own compact (p,g) list in LDS from chunk-interleaved cells
//      (chunks c == s mod NS; sin/cos hoisted to once per block),
//   B) runs the R8 register-tiled dots loop off that LDS list with ds_add_f32
//      deposits into a private 32 KB LDS score tile,
//   C) writes its partial; the last block per ROI (device-scope done counter,
//      threadfence release/acquire) merges NS partials + argmax + writes out.
template <int NS, int CAP>
__global__ __launch_bounds__(256) void k_fused(
        const float* __restrict__ rois, const float* __restrict__ pbox,
        const float* __restrict__ vfeat, const float* __restrict__ fproto,
        const int* __restrict__ v2p, float* __restrict__ partial,
        int* __restrict__ done, float* __restrict__ out) {
    __shared__ float    sscore[GCELLS];        // 32 KB (aliased as u64[256] in C)
    __shared__ float    sfeat[TROWS * FPAD];   // 16.9 KB
    __shared__ unsigned sg[TROWS];
    __shared__ unsigned llist[CAP];            // local compact list
    __shared__ int      lcnt;
    __shared__ int      slast;

    const int m    = blockIdx.x & 63;
    const int s    = blockIdx.x >> 6;          // slice 0..NS-1
    const int tid  = threadIdx.x;
    const int w    = tid >> 6;                 // wave 0..3
    const int lane = tid & 63;
    const float* roi = rois + m * 7;

    if (tid == 0) lcnt = 0;
    {   // zero the private score tile
        float4* s4 = (float4*)sscore;
        #pragma unroll
        for (int i = 0; i < GCELLS / 4 / 256; ++i)
            s4[tid + 256 * i] = make_float4(0.f, 0.f, 0.f, 0.f);
    }
    __syncthreads();                           // lcnt=0 visible

    // ---- A: build local list (chunks of 64 cells, c = s + NS*j, wave j%4) ----
    {
        float bx, by, bz, cs, sn, ox, oy, oz;
        {
#pragma clang fp contract(off)
            bx = roi[3] * 2.0f; by = roi[4] * 2.0f; bz = roi[5];
            cs = cosf(roi[6]);  sn = sinf(roi[6]);
            ox = roi[0]; oy = roi[1]; oz = roi[2];
        }
        for (int j = w; s + NS * j < GCELLS / 64; j += 4) {
            int g = (s + NS * j) * 64 + lane;
            int p = cell_probe(bx, by, bz, cs, sn, ox, oy, oz, g, v2p);
            bool v = p >= 0;
            unsigned long long bal = __ballot(v);
            int nset = __popcll(bal);
            int base = 0;
            if (lane == 0 && nset) base = atomicAdd(&lcnt, nset);
            base = __shfl(base, 0, 64);
            if (v) {
                int pos = __popcll(bal & ((1ull << lane) - 1ull));
                llist[base + pos] = ((unsigned)p << 13) | (unsigned)g;
            }
        }
    }
    __syncthreads();
    const int n = lcnt;

    // ---- B: register-tiled dots off the LDS list ----
    {
        const int vi = lane & 7;
        const int ti = (lane >> 3) & 7;
        const int tbase = w * 40 + ti;         // taps: tbase + 8b, b=0..4

        int tkx[5], tky[5], tkz[5], tok[5];
        #pragma unroll
        for (int b = 0; b < 5; ++b) {
            int t = tbase + 8 * b;
            tok[b] = t < NTAPS;
            int tc = tok[b] ? t : (NTAPS - 1);
            int kx  = tc / 21;
            int rem = tc - kx * 21;
            tkx[b] = kx;
            tky[b] = rem / 3;
            tkz[b] = rem - tky[b] * 3;
        }

        for (int vt0 = 0; vt0 < n; vt0 += TROWS) {
            __syncthreads();                   // prior deposits done (sg/sfeat reuse)
            {   // stage 32 feat rows: 8 threads per row, 16 floats each
                int r = tid >> 3;
                int q = tid & 7;
                int v = vt0 + r;
                unsigned e = 0xFFFFFFFFu;
                if (v < n) e = llist[v];
                if (q == 0) sg[r] = e;
                if (e != 0xFFFFFFFFu) {
                    int p = (int)(e >> 13);
                    const float4* src = (const float4*)(vfeat + (size_t)p * CCH) + q * 4;
                    float4* drow = (float4*)(sfeat + r * FPAD + q * 16);
                    #pragma unroll
                    for (int j = 0; j < 4; ++j) drow[j] = src[j];
                }
            }
            __syncthreads();

            float acc[4][5];
            #pragma unroll
            for (int a = 0; a < 4; ++a)
                #pragma unroll
                for (int b = 0; b < 5; ++b) acc[a][b] = 0.0f;

            #pragma unroll 1
            for (int k = 0; k < CCH; k += 4) {
                float4 f[4];
                #pragma unroll
                for (int a = 0; a < 4; ++a)
                    f[a] = *(const float4*)&sfeat[(vi + 8 * a) * FPAD + k];
                float4 wv[5];
                #pragma unroll
                for (int b = 0; b < 5; ++b)
                    wv[b] = *(const float4*)(fproto + (tbase + (tok[b] ? 8 * b : 0)) * CCH + k);
                #pragma unroll
                for (int a = 0; a < 4; ++a)
                    #pragma unroll
                    for (int b = 0; b < 5; ++b) {
                        acc[a][b] = fmaf(f[a].x, wv[b].x, acc[a][b]);
                        acc[a][b] = fmaf(f[a].y, wv[b].y, acc[a][b]);
                        acc[a][b] = fmaf(f[a].z, wv[b].z, acc[a][b]);
                        acc[a][b] = fmaf(f[a].w, wv[b].w, acc[a][b]);
                    }
            }

            // deposit dots into the private LDS score grid (ds_add_f32)
            #pragma unroll
            for (int b = 0; b < 5; ++b) {
                if (!tok[b]) continue;
                #pragma unroll
                for (int a = 0; a < 4; ++a) {
                    unsigned e = sg[vi + 8 * a];
                    if (e == 0xFFFFFFFFu) continue;
                    int g  = (int)(e & 8191u);
                    int cx = (g >> 7)        - (tkx[b] - 3);
                    int cy = ((g >> 2) & 31) - (tky[b] - 3);
                    int cz = (g & 3)         - (tkz[b] - 1);
                    if ((unsigned)cx < (unsigned)GXD && (unsigned)cy < (unsigned)GYD &&
                        (unsigned)cz < (unsigned)GZD)
                        atomicAdd(&sscore[(cx << 7) | (cy << 2) | cz], acc[a][b]);
                }
            }
        }
    }

    // ---- C: partial writeback, then last block per ROI merges + argmax ----
    __syncthreads();                           // all deposits done
    {
        float* dst = partial + ((size_t)m * NS + s) * GCELLS;
        const float4* s4 = (const float4*)sscore;
        float4* d4 = (float4*)dst;
        #pragma unroll
        for (int i = 0; i < GCELLS / 4 / 256; ++i)
            d4[tid + 256 * i] = s4[tid + 256 * i];
    }
    __threadfence();                           // release: partial visible device-wide
    __syncthreads();
    if (tid == 0) slast = (atomicAdd(&done[m], 1) == NS - 1) ? 1 : 0;
    __syncthreads();
    if (!slast) return;
    __threadfence();                           // acquire: see all slices' partials

    const float* basep = partial + (size_t)m * NS * GCELLS;
    unsigned long long bk = 0ull;
    #pragma unroll 1
    for (int i = 0; i < GCELLS / 256; ++i) {
        int g = tid + 256 * i;
        float v = 0.0f;
        #pragma unroll
        for (int q = 0; q < NS; ++q) v += basep[q * GCELLS + g];
        unsigned ub  = __float_as_uint(v);
        unsigned key = (ub & 0x80000000u) ? ~ub : (ub | 0x80000000u);  // order-preserving
        unsigned long long pk =
            ((unsigned long long)key << 32) | (unsigned)(GCELLS - 1 - g);  // ties -> smallest g
        bk = bk > pk ? bk : pk;
    }
    unsigned long long* red = reinterpret_cast<unsigned long long*>(sscore);
    red[tid] = bk;
    __syncthreads();
    for (int st = 128; st > 0; st >>= 1) {
        if (tid < st) {
            unsigned long long o = red[tid + st];
            if (o > red[tid]) red[tid] = o;
        }
        __syncthreads();
    }
    if (tid == 0) {
        int g = (GCELLS - 1) - (int)(unsigned)(red[0] & 0xFFFFFFFFu);
        float X, Y, Z;
        cell_xyz(roi, g, X, Y, Z);
        out[m * 7 + 0] = X;
        out[m * 7 + 1] = Y;
        out[m * 7 + 2] = Z;
        out[m * 7 + 3] = pbox[3];
        out[m * 7 + 4] = pbox[4];
        out[m * 7 + 5] = pbox[5];
        out[m * 7 + 6] = pbox[6];
    }
}

extern "C" void kernel_launch(void* const* d_in, const int* in_sizes, int n_in,
                              void* d_out, int out_size, void* d_ws, size_t ws_size,
                              hipStream_t stream) {
    const float* rois    = (const float*)d_in[0];
    const float* pbox    = (const float*)d_in[1];
    const float* vfeat   = (const float*)d_in[2];
    const float* fproto  = (const float*)d_in[3];
    const int*   vcoords = (const int*)d_in[4];
    float* out = (float*)d_out;

    // ws layout: v2p | partial (NS slices) | done
    int*   v2p = (int*)d_ws;                                   // NGRID ints (5.63 MB)
    float* partial = (float*)(v2p + NGRID);

    size_t need12 = (size_t)NGRID * 4 + (size_t)12 * MROI * GCELLS * 4 + 256;
    size_t need4  = (size_t)NGRID * 4 + (size_t)4  * MROI * GCELLS * 4 + 256;

    hipMemsetAsync(v2p, 0xFF, (size_t)NGRID * 4, stream);      // v2p = -1

    if (ws_size >= need12) {
        int* done = (int*)(partial + (size_t)12 * MROI * GCELLS);
        k_scatter<<<(NVOX + 255) / 256, 256, 0, stream>>>(vcoords, v2p, done);
        k_fused<12, 704><<<12 * MROI, 256, 0, stream>>>(
            rois, pbox, vfeat, fproto, v2p, partial, done, out);
    } else {
        // fallback: 4 slices (needs 8.4 MB partial; LDS 58 KB -> 2 blocks/CU)
        int* done = (int*)(partial + (size_t)4 * MROI * GCELLS);
        (void)need4;
        k_scatter<<<(NVOX + 255) / 256, 256, 0, stream>>>(vcoords, v2p, done);
        k_fused<4, 2048><<<4 * MROI, 256, 0, stream>>>(
            rois, pbox, vfeat, fproto, v2p, partial, done, out);
    }
}